// Round 8
// baseline (300.605 us; speedup 1.0000x reference)
//
#include <hip/hip_runtime.h>
#include <stdint.h>

#define VOCAB  32000
#define NSTATE 64
#define NLABEL 16
#define BATCH  512
#define MAXLEN 512
#define NCHUNK (MAXLEN / 16)   // 32 chunks of 16 timesteps

#define LOG2E 1.44269504088896340736f
#define LN2_D 0.69314718055994530942

typedef float v2f __attribute__((ext_vector_type(2)));

#if defined(__has_builtin) && __has_builtin(__builtin_amdgcn_exp2f)
#define EXP2(x) __builtin_amdgcn_exp2f(x)
#else
#define EXP2(x) exp2f(x)
#endif
#if defined(__has_builtin) && __has_builtin(__builtin_amdgcn_logf)
#define LOG2(x) __builtin_amdgcn_logf(x)   // v_log_f32 = log2
#else
#define LOG2(x) log2f(x)
#endif

#define SBAR() __builtin_amdgcn_sched_barrier(0)

__device__ __forceinline__ float wave_max64(float x) {
#pragma unroll
  for (int off = 32; off > 0; off >>= 1) x = fmaxf(x, __shfl_xor(x, off, 64));
  return x;
}
__device__ __forceinline__ float wave_sum64(float x) {
#pragma unroll
  for (int off = 32; off > 0; off >>= 1) x += __shfl_xor(x, off, 64);
  return x;
}
__device__ __forceinline__ float bcast0(float x) {
  return __uint_as_float(__builtin_amdgcn_readfirstlane(__float_as_uint(x)));
}
__device__ __forceinline__ double shfl_xor_d(double x, int off) {
  union { double d; int i[2]; } u;
  u.d = x;
  u.i[0] = __shfl_xor(u.i[0], off, 64);
  u.i[1] = __shfl_xor(u.i[1], off, 64);
  return u.d;
}

// --- prep 1: emb2[w][s] = log2_softmax(emb[w]*log2e) ---
__global__ void prep_emb_k(const float* __restrict__ emb, float* __restrict__ emb2) {
  const int w = blockIdx.x * 4 + (threadIdx.x >> 6);
  const int s = threadIdx.x & 63;
  const float v = emb[w * NSTATE + s] * LOG2E;
  const float m = wave_max64(v);
  const float ss = wave_sum64(EXP2(v - m));
  emb2[w * NSTATE + s] = v - m - LOG2(ss);
}

// --- prep 2: W = softmax(transition) rows; out2 = log2_softmax(output) rows ---
__global__ void prep_mats_k(const float* __restrict__ trans, const float* __restrict__ outp,
                            float* __restrict__ W, float* __restrict__ out2) {
  const int r = blockIdx.x, s = threadIdx.x;
  if (r < NSTATE) {
    const float v = trans[r * NSTATE + s] * LOG2E;
    const float m = wave_max64(v);
    const float ss = wave_sum64(EXP2(v - m));
    W[r * NSTATE + s] = EXP2(v - m - LOG2(ss));
  } else {
    const int l = r - NSTATE;
    const float v = outp[l * NSTATE + s] * LOG2E;
    const float m = wave_max64(v);
    const float ss = wave_sum64(EXP2(v - m));
    out2[l * NSTATE + s] = v - m - LOG2(ss);
  }
}

// --- prep 3: gather per-(b,t) emission factors, transposed chunk-blocked ---
// qT[((b*NCHUNK + t/16)*NSTATE + s)*16 + t%16] = 2^(emb2[id][s] - emb2[id][0])
// mu[b*MAXLEN + t] = emb2[id][0]
__global__ void prep_gather_k(const int* __restrict__ sents,
                              const float* __restrict__ emb2,
                              float* __restrict__ qT, float* __restrict__ mu) {
  const int b = blockIdx.x >> 3;
  const int tile = blockIdx.x & 7;   // 8 tiles of 64 timesteps
  const int s = threadIdx.x;
  __shared__ float tileb[64][65];    // [t_in_tile][state], +1 pad

  const int* sentrow = sents + b * MAXLEN + tile * 64;
#pragma unroll 4
  for (int tt = 0; tt < 64; ++tt) {
    const int id = sentrow[tt];                   // wave-uniform
    const float e = emb2[id * NSTATE + s];
    const float e0 = bcast0(e);
    tileb[tt][s] = EXP2(e - e0);
    if (s == 0) mu[b * MAXLEN + tile * 64 + tt] = e;
  }
  __syncthreads();

  // writeout: lane plays t-within-tile role
  const int lt = s;
  const int chunk = tile * 4 + (lt >> 4);
  const int tc = lt & 15;
  float* dst = qT + ((size_t)(b * NCHUNK + chunk) * NSTATE) * 16 + tc;
#pragma unroll 8
  for (int i = 0; i < NSTATE; ++i) {
    dst[(size_t)i * 16] = tileb[lt][i];           // conflict-free: bank (lt+i)%32
  }
}

// --- prep 4: musum[b] = sum_{t<len} mu[b][t] in f64 ---
__global__ void prep_musum_k(const float* __restrict__ mu, const int* __restrict__ length,
                             double* __restrict__ musum) {
  const int b = blockIdx.x;
  const int lane = threadIdx.x;
  const int len = length[b];
  double acc = 0.0;
#pragma unroll
  for (int k = 0; k < 8; ++k) {
    const int t = k * 64 + lane;
    const float v = mu[b * MAXLEN + t];
    if (t < len) acc += (double)v;
  }
#pragma unroll
  for (int off = 32; off > 0; off >>= 1) acc += shfl_xor_d(acc, off);
  if (lane == 0) musum[b] = acc;
}

// 64-wide dot of W-rows (in regs) against broadcast LDS vector
__device__ __forceinline__ float dot64(const float* __restrict__ pl,
                                       const v2f* __restrict__ w2) {
  const float4* pb4 = reinterpret_cast<const float4*>(pl);
  v2f A0{0.f, 0.f}, A1 = A0, A2 = A0, A3 = A0, A4 = A0, A5 = A0, A6 = A0, A7 = A0;
#pragma unroll
  for (int j = 0; j < 4; ++j) {
    const float4 qa = pb4[4 * j + 0];
    const float4 qb = pb4[4 * j + 1];
    const float4 qc = pb4[4 * j + 2];
    const float4 qd = pb4[4 * j + 3];
    A0 = __builtin_elementwise_fma(w2[8 * j + 0], v2f{qa.x, qa.y}, A0);
    A1 = __builtin_elementwise_fma(w2[8 * j + 1], v2f{qa.z, qa.w}, A1);
    A2 = __builtin_elementwise_fma(w2[8 * j + 2], v2f{qb.x, qb.y}, A2);
    A3 = __builtin_elementwise_fma(w2[8 * j + 3], v2f{qb.z, qb.w}, A3);
    A4 = __builtin_elementwise_fma(w2[8 * j + 4], v2f{qc.x, qc.y}, A4);
    A5 = __builtin_elementwise_fma(w2[8 * j + 5], v2f{qc.z, qc.w}, A5);
    A6 = __builtin_elementwise_fma(w2[8 * j + 6], v2f{qd.x, qd.y}, A6);
    A7 = __builtin_elementwise_fma(w2[8 * j + 7], v2f{qd.z, qd.w}, A7);
  }
  const v2f S0 = A0 + A4, S1 = A1 + A5, S2 = A2 + A6, S3 = A3 + A7;
  const v2f T0 = S0 + S2, T1 = S1 + S3;
  const v2f U = T0 + T1;
  return U.x + U.y;
}

// --- main: one wave per TWO batch rows (interleaved, independent chains) ---
// p <- (W·p) * q[t]; q precomputed; exact pow2 renorm every 4 steps.
// __launch_bounds__(64, 1): min 1 wave/EU -> VGPR cap 512, W stays resident
// (without it the backend targets high occupancy and SPILLS the W array:
//  rounds 3/5 reported VGPR_Count 48-60 < the 90+ live values -> scratch
//  reloads every step were the ~930 cyc/step mystery).
__global__ __launch_bounds__(64, 1) void iohmm_fwd3(
    const int* __restrict__ length, const float* __restrict__ W,
    const float* __restrict__ out2, const float* __restrict__ qT,
    const double* __restrict__ musum, float* __restrict__ score) {
  const int b0 = blockIdx.x * 2;
  const int b1 = b0 + 1;
  const int s = threadIdx.x;
  __shared__ __align__(16) float pl0[NSTATE];
  __shared__ __align__(16) float pl1[NSTATE];

  // W row s as 32 packed float2 (64 VGPRs), shared by both rows
  v2f w2[NSTATE / 2];
#pragma unroll
  for (int j = 0; j < 16; ++j) {
    const float4 q = *reinterpret_cast<const float4*>(W + s * NSTATE + 4 * j);
    w2[2 * j + 0] = v2f{q.x, q.y};
    w2[2 * j + 1] = v2f{q.z, q.w};
  }

  const int len0 = length[b0];
  const int len1 = length[b1];
  const int lmax = len0 > len1 ? len0 : len1;
  const int nch = (lmax + 15) >> 4;

  const float4* q0b = reinterpret_cast<const float4*>(qT) +
                      ((size_t)b0 * NCHUNK * NSTATE + s) * 4;
  const float4* q1b = reinterpret_cast<const float4*>(qT) +
                      ((size_t)b1 * NCHUNK * NSTATE + s) * 4;

  float pA, pB;
  int mu0i = 0, mu1i = 0;

  auto dostep = [&](int t, float q0v, float q1v, bool rn) {
    pl0[s] = pA;                 // single-wave: in-order LDS, no barrier needed
    pl1[s] = pB;
    SBAR();
    const float s0 = dot64(pl0, w2);   // two independent dots: scheduler
    const float s1 = dot64(pl1, w2);   // interleaves them (latency hiding)
    SBAR();
    if (t < len0) {
      pA = s0 * q0v;
      if (rn) {
        const uint32_t u = __builtin_amdgcn_readfirstlane(__float_as_uint(pA));
        const int ex = (int)((u >> 23) & 255u) - 127;
        pA *= __uint_as_float((uint32_t)(127 - ex) << 23);
        mu0i += ex;
      }
    }
    if (t < len1) {
      pB = s1 * q1v;
      if (rn) {
        const uint32_t u = __builtin_amdgcn_readfirstlane(__float_as_uint(pB));
        const int ex = (int)((u >> 23) & 255u) - 127;
        pB *= __uint_as_float((uint32_t)(127 - ex) << 23);
        mu1i += ex;
      }
    }
  };

  auto do16 = [&](int c, const float4& P0, const float4& P1, const float4& P2,
                  const float4& P3, const float4& R0, const float4& R1,
                  const float4& R2, const float4& R3, bool skip0) {
    const int t0 = c * 16;
    if (!skip0) dostep(t0 + 0, P0.x, R0.x, true);
    dostep(t0 + 1, P0.y, R0.y, false);
    dostep(t0 + 2, P0.z, R0.z, false);
    dostep(t0 + 3, P0.w, R0.w, false);
    dostep(t0 + 4, P1.x, R1.x, true);
    dostep(t0 + 5, P1.y, R1.y, false);
    dostep(t0 + 6, P1.z, R1.z, false);
    dostep(t0 + 7, P1.w, R1.w, false);
    dostep(t0 + 8, P2.x, R2.x, true);
    dostep(t0 + 9, P2.y, R2.y, false);
    dostep(t0 + 10, P2.z, R2.z, false);
    dostep(t0 + 11, P2.w, R2.w, false);
    dostep(t0 + 12, P3.x, R3.x, true);
    dostep(t0 + 13, P3.y, R3.y, false);
    dostep(t0 + 14, P3.z, R3.z, false);
    dostep(t0 + 15, P3.w, R3.w, false);
  };

  // chunk register buffers: per row, double-buffered (16-step prefetch distance)
  float4 A00, A01, A02, A03, B00, B01, B02, B03;   // row0
  float4 A10, A11, A12, A13, B10, B11, B12, B13;   // row1
#define LOADC0(c, r0, r1, r2, r3) { const float4* p4_ = q0b + (size_t)(c) * (NSTATE * 4); \
    r0 = p4_[0]; r1 = p4_[1]; r2 = p4_[2]; r3 = p4_[3]; }
#define LOADC1(c, r0, r1, r2, r3) { const float4* p4_ = q1b + (size_t)(c) * (NSTATE * 4); \
    r0 = p4_[0]; r1 = p4_[1]; r2 = p4_[2]; r3 = p4_[3]; }

  LOADC0(0, A00, A01, A02, A03);
  LOADC1(0, A10, A11, A12, A13);
  {
    const int c1 = 1 < NCHUNK ? 1 : NCHUNK - 1;
    LOADC0(c1, B00, B01, B02, B03);
    LOADC1(c1, B10, B11, B12, B13);
  }

  pA = A00.x;  // t=0: p0[s] = q[b][0][s] (lane0 == 1 by construction)
  pB = A10.x;

  for (int c = 0; c < nch; c += 2) {
    do16(c, A00, A01, A02, A03, A10, A11, A12, A13, c == 0);
    {
      int cn = c + 2; if (cn >= NCHUNK) cn = NCHUNK - 1;
      LOADC0(cn, A00, A01, A02, A03);      // prefetch: consumed 16 steps later
      LOADC1(cn, A10, A11, A12, A13);
    }
    if (c + 1 < nch) do16(c + 1, B00, B01, B02, B03, B10, B11, B12, B13, false);
    {
      int cn = c + 3; if (cn >= NCHUNK) cn = NCHUNK - 1;
      LOADC0(cn, B00, B01, B02, B03);
      LOADC1(cn, B10, B11, B12, B13);
    }
  }
#undef LOADC0
#undef LOADC1

  // epilogue per row: score[b][l] = (musum[b]+MUi + lse2_s(out2[l][s]+log2 p))*ln2
  {
    const float f = LOG2(pA);
    const double base = musum[b0] + (double)mu0i;
    for (int l = 0; l < NLABEL; ++l) {
      const float y = out2[l * NSTATE + s] + f;
      const float m = wave_max64(y);
      const float ssum = wave_sum64(EXP2(y - m));
      if (s == 0)
        score[b0 * NLABEL + l] = (float)((base + (double)m + (double)LOG2(ssum)) * LN2_D);
    }
  }
  {
    const float f = LOG2(pB);
    const double base = musum[b1] + (double)mu1i;
    for (int l = 0; l < NLABEL; ++l) {
      const float y = out2[l * NSTATE + s] + f;
      const float m = wave_max64(y);
      const float ssum = wave_sum64(EXP2(y - m));
      if (s == 0)
        score[b1 * NLABEL + l] = (float)((base + (double)m + (double)LOG2(ssum)) * LN2_D);
    }
  }
}

// ================= fallback (if ws too small), with the spill fix =================
template <bool PRE>
__global__ __launch_bounds__(64, 1) void iohmm_fwd(
    const int* __restrict__ sents, const int* __restrict__ length,
    const float* __restrict__ emb, const float* __restrict__ trans,
    const float* __restrict__ outp, const float* __restrict__ emb2,
    const float* __restrict__ W, const float* __restrict__ out2,
    float* __restrict__ score) {
  const int b = blockIdx.x;
  const int s = threadIdx.x;
  __shared__ __align__(16) float p_lds[2][NSTATE];
  __shared__ __align__(16) int s_ids[MAXLEN];
  {
    const int4* s4 = reinterpret_cast<const int4*>(sents + b * MAXLEN);
    int4 c0 = s4[s];
    int4 c1 = s4[64 + s];
    reinterpret_cast<int4*>(s_ids)[s] = c0;
    reinterpret_cast<int4*>(s_ids)[64 + s] = c1;
  }
  v2f w2[NSTATE / 2];
  if (PRE) {
#pragma unroll
    for (int j = 0; j < 16; ++j) {
      const float4 q = *reinterpret_cast<const float4*>(W + s * NSTATE + 4 * j);
      w2[2 * j + 0] = v2f{q.x, q.y};
      w2[2 * j + 1] = v2f{q.z, q.w};
    }
  } else {
    float wr[NSTATE];
#pragma unroll
    for (int j = 0; j < 16; ++j) {
      const float4 q = *reinterpret_cast<const float4*>(trans + s * NSTATE + 4 * j);
      wr[4 * j + 0] = q.x * LOG2E; wr[4 * j + 1] = q.y * LOG2E;
      wr[4 * j + 2] = q.z * LOG2E; wr[4 * j + 3] = q.w * LOG2E;
    }
    float m = -1e30f;
#pragma unroll
    for (int j = 0; j < NSTATE; ++j) m = fmaxf(m, wr[j]);
    float ss = 0.f;
#pragma unroll
    for (int j = 0; j < NSTATE; ++j) ss += EXP2(wr[j] - m);
    const float d = m + LOG2(ss);
#pragma unroll
    for (int j = 0; j < NSTATE / 2; ++j)
      w2[j] = v2f{EXP2(wr[2 * j] - d), EXP2(wr[2 * j + 1] - d)};
  }
  const int len = length[b];
  __syncthreads();
  auto EMIT = [&](int t) -> float {
    const int tc = t < MAXLEN ? t : MAXLEN - 1;
    const int id = s_ids[tc];
    return PRE ? emb2[id * NSTATE + s] : emb[id * NSTATE + s] * LOG2E;
  };
  float e0 = EMIT(0);
  if (!PRE) {
    const float dm = wave_max64(e0);
    const float dsum = wave_sum64(EXP2(e0 - dm));
    e0 = e0 - dm - LOG2(dsum);
  }
  const float se0 = bcast0(e0);
  float p = EXP2(e0 - se0);
  double MU = (double)se0;
  int MUi = 0;
  float eA = EMIT(1), eB = EMIT(2), eC = EMIT(3);
  for (int t = 1; t < len; ++t) {
    float* pb = p_lds[t & 1];
    pb[s] = p;
    SBAR();
    const float eN = EMIT(t + 3);
    const float sum = dot64(pb, w2);
    SBAR();
    float e;
    if (PRE) {
      e = eA;
    } else {
      const float dm = wave_max64(eA);
      const float dsum = wave_sum64(EXP2(eA - dm));
      e = eA - dm - LOG2(dsum);
    }
    const float se = bcast0(e);
    const float q = EXP2(e - se);
    p = sum * q;
    if ((t & 15) == 0) {
      const uint32_t u = __builtin_amdgcn_readfirstlane(__float_as_uint(p));
      const int ex = (int)((u >> 23) & 255u) - 127;
      p *= __uint_as_float((uint32_t)(127 - ex) << 23);
      MUi += ex;
    }
    MU += (double)se;
    eA = eB; eB = eC; eC = eN;
  }
  const float f = LOG2(p);
  const double MUt = MU + (double)MUi;
  for (int l = 0; l < NLABEL; ++l) {
    float y;
    if (PRE) {
      y = out2[l * NSTATE + s] + f;
    } else {
      const float v = outp[l * NSTATE + s] * LOG2E;
      const float lm = wave_max64(v);
      const float lsum = wave_sum64(EXP2(v - lm));
      y = v - lm - LOG2(lsum) + f;
    }
    const float m = wave_max64(y);
    const float ssum = wave_sum64(EXP2(y - m));
    if (s == 0) {
      const double sc = MUt + (double)m + (double)LOG2(ssum);
      score[b * NLABEL + l] = (float)(sc * LN2_D);
    }
  }
}

extern "C" void kernel_launch(void* const* d_in, const int* in_sizes, int n_in,
                              void* d_out, int out_size, void* d_ws, size_t ws_size,
                              hipStream_t stream) {
  const int* sents = (const int*)d_in[0];
  const int* length = (const int*)d_in[1];
  const float* emb = (const float*)d_in[2];
  const float* trans = (const float*)d_in[3];
  const float* outp = (const float*)d_in[4];
  float* score = (float*)d_out;

  // ws layout (bytes)
  const size_t emb2_off = 0;
  const size_t emb2_sz = (size_t)VOCAB * NSTATE * sizeof(float);          // 8,192,000
  const size_t qT_off = emb2_off + emb2_sz;
  const size_t qT_sz = (size_t)BATCH * NCHUNK * NSTATE * 16 * sizeof(float);  // 67,108,864
  const size_t mu_off = qT_off + qT_sz;
  const size_t mu_sz = (size_t)BATCH * MAXLEN * sizeof(float);            // 1,048,576
  const size_t musum_off = mu_off + mu_sz;
  const size_t musum_sz = (size_t)BATCH * sizeof(double);                 // 4,096
  const size_t W_off = musum_off + musum_sz;
  const size_t W_sz = NSTATE * NSTATE * sizeof(float);
  const size_t out2_off = W_off + W_sz;
  const size_t out2_sz = NLABEL * NSTATE * sizeof(float);
  const size_t need2 = out2_off + out2_sz;                                // ~76.4 MB

  const size_t need1 = emb2_sz + W_sz + out2_sz;                          // ~8.2 MB

  if (ws_size >= need2) {
    float* emb2 = (float*)((char*)d_ws + emb2_off);
    float* qT = (float*)((char*)d_ws + qT_off);
    float* mu = (float*)((char*)d_ws + mu_off);
    double* musum = (double*)((char*)d_ws + musum_off);
    float* W = (float*)((char*)d_ws + W_off);
    float* out2 = (float*)((char*)d_ws + out2_off);
    prep_emb_k<<<VOCAB / 4, 256, 0, stream>>>(emb, emb2);
    prep_mats_k<<<NSTATE + NLABEL, 64, 0, stream>>>(trans, outp, W, out2);
    prep_gather_k<<<BATCH * 8, 64, 0, stream>>>(sents, emb2, qT, mu);
    prep_musum_k<<<BATCH, 64, 0, stream>>>(mu, length, musum);
    iohmm_fwd3<<<BATCH / 2, 64, 0, stream>>>(length, W, out2, qT, musum, score);
  } else if (ws_size >= need1) {
    float* emb2 = (float*)d_ws;
    float* W = (float*)((char*)d_ws + emb2_sz);
    float* out2 = (float*)((char*)d_ws + emb2_sz + W_sz);
    prep_emb_k<<<VOCAB / 4, 256, 0, stream>>>(emb, emb2);
    prep_mats_k<<<NSTATE + NLABEL, 64, 0, stream>>>(trans, outp, W, out2);
    iohmm_fwd<true><<<BATCH, 64, 0, stream>>>(sents, length, emb, trans, outp,
                                              emb2, W, out2, score);
  } else {
    iohmm_fwd<false><<<BATCH, 64, 0, stream>>>(sents, length, emb, trans, outp,
                                               nullptr, nullptr, nullptr, score);
  }
}